// Round 3
// baseline (1080.851 us; speedup 1.0000x reference)
//
#include <hip/hip_runtime.h>

#define NB 8
#define NN 8192
#define NC 32
#define NPOINT 1024
#define NSAMPLE 32

// Exact round-to-nearest distance, no fma contraction: matches numpy
// ((dx*dx + dy*dy) + dz*dz) bitwise.
__device__ __forceinline__ float d2_exact(float ax, float ay, float az,
                                          float bx, float by, float bz) {
    float dx = __fsub_rn(ax, bx);
    float dy = __fsub_rn(ay, by);
    float dz = __fsub_rn(az, bz);
    return __fadd_rn(__fadd_rn(__fmul_rn(dx, dx), __fmul_rn(dy, dy)),
                     __fmul_rn(dz, dz));
}

// ---------------------------------------------------------------------------
// Round-6: fused cooperative launch (round-2 structure, kept) + FPS inner
// loop rework targeting the measured ~2136 cyc/iter serial chain:
//   (a) coord+dist arrays pinned in ARCH VGPRs inside the loop (round-0/2
//       VGPR_Count=88/132 < 128 needed => allocator parked arrays in AGPRs,
//       paying accvgpr shuttles every access),
//   (b) 4 independent argmax chains (dep depth 32 -> 8), contiguous k-ranges
//       so lower chain wins ties == first-occurrence semantics,
//   (c) batch coords staged in LDS: winner fetch = uniform ds_read (~120cy)
//       instead of readfirstlane+L2 (~200cy),
//   (d) in-loop barrier is s_waitcnt lgkmcnt(0); s_barrier — no vmcnt(0)
//       drain, so the cross-XCD publish atomics (600-900cy ack) stop
//       stalling all 4 waves every 16th iteration. The atomic carries its
//       own payload; no ordering is needed beyond its eventual arrival.
// Producers: blocks 0..7 (one per batch). Consumers: blocks 8..255,
// persistent, chasing the publication frontier ordered by (t, b).
// ---------------------------------------------------------------------------
#define FPS_T 256
#define FPS_K (NN / FPS_T)   // 32 points per thread
#define NCONS 248
#define NBLK (NB + NCONS)    // 256 blocks, 1 per CU
#define K2_WAVES 4
#define SLOTS_PER_PASS (NCONS * K2_WAVES)                              // 992
#define NPASS ((NB * NPOINT + SLOTS_PER_PASS - 1) / SLOTS_PER_PASS)    // 9

#define XS 37   // X row stride (35 cols + pad)
#define HS 65   // H row stride (64 cols + pad)

// shared-memory union layout (bytes):
//   producer: redk[2][4] ull @0 (64), sel_hist[1024] int @64 (4096),
//             sxyz[8192*3] f32 @4160 (98304)  -> 102464 used
//   consumer: sel_s[4][32] int @0 (512), bufA[4][2080] f32 @512 (33280),
//             bufB[4][2080] f32 @33792 (33280) -> 67072 used
// 102464 > 81920 guarantees 1 block/CU (2 blocks would exceed 160 KB).
#define SMEM_BYTES 102464

__device__ __forceinline__ unsigned long long kmax64(unsigned long long a,
                                                     unsigned long long b) {
    return a > b ? a : b;
}

template <int CTRL, int RM>
__device__ __forceinline__ unsigned long long dpp_k(unsigned long long k) {
    unsigned hi = (unsigned)__builtin_amdgcn_update_dpp(
        0, (int)(k >> 32), CTRL, RM, 0xf, true);
    unsigned lo = (unsigned)__builtin_amdgcn_update_dpp(
        0, (int)(k & 0xffffffffULL), CTRL, RM, 0xf, true);
    return ((unsigned long long)hi << 32) | lo;
}

// Workgroup barrier that drains LDS ops only (no vmcnt(0)): keeps the
// fire-and-forget publish atomics off the barrier critical path.
__device__ __forceinline__ void barrier_lds_only() {
    asm volatile("s_waitcnt lgkmcnt(0)\n\ts_barrier" ::: "memory");
}

__global__ __launch_bounds__(256, 1) void fused_kernel(
    const float* __restrict__ xyz, const float* __restrict__ normal,
    const float* __restrict__ features,
    const float* __restrict__ w1, const float* __restrict__ b1,
    const float* __restrict__ w2, const float* __restrict__ b2,
    const float* __restrict__ w3, const float* __restrict__ b3,
    float* __restrict__ out_xyz, float* __restrict__ out_normal,
    float* __restrict__ out_feat, int* __restrict__ idxbuf) {

    __shared__ __align__(16) char smem[SMEM_BYTES];

    if (blockIdx.x < NB) {
        // ================= producer: FPS ===================================
        unsigned long long (*redk)[4] = (unsigned long long (*)[4])(smem);
        int*   sel_hist = (int*)(smem + 64);
        float* sxyz     = (float*)(smem + 64 + 4096);

        const int b = blockIdx.x;
        const float* bx = xyz + (size_t)b * NN * 3;
        const int tid = threadIdx.x;
        const int lane = tid & 63;
        const int wave = tid >> 6;   // 0..3
        int* idxg = idxbuf + (b << 10);

        float px[FPS_K], py[FPS_K], pz[FPS_K], dist[FPS_K];
#pragma unroll
        for (int k = 0; k < FPS_K; ++k) {
            int p = tid + k * FPS_T;
            float x = bx[p * 3 + 0];
            float y = bx[p * 3 + 1];
            float z = bx[p * 3 + 2];
            px[k] = x; py[k] = y; pz[k] = z;
            sxyz[p * 3 + 0] = x;
            sxyz[p * 3 + 1] = y;
            sxyz[p * 3 + 2] = z;
            dist[k] = 1e10f;
        }

        int cur = 0;
        float lx = bx[0], ly = bx[1], lz = bx[2];

        for (int it = 0; it < NPOINT; ++it) {
            const int par = it & 1;
            if (tid == 0) sel_hist[it] = cur;

            // Pin all per-point state in ARCH VGPRs at every iteration:
            // without this the allocator parks the arrays in AGPRs and pays
            // v_accvgpr_read/write on every access in the hot loop.
#pragma unroll
            for (int k = 0; k < FPS_K; ++k) {
                asm volatile("" : "+v"(px[k]), "+v"(py[k]), "+v"(pz[k]),
                                  "+v"(dist[k]));
            }

            // 4 independent argmax chains over contiguous k-ranges
            // (dep depth 8 instead of 32). Lower chain owns lower k ->
            // strict > at every combine keeps first occurrence.
            float bv[4] = {-1.0f, -1.0f, -1.0f, -1.0f};
            int bk[4] = {0, 0, 0, 0};
#pragma unroll
            for (int k = 0; k < FPS_K; ++k) {
                const int c = k >> 3;
                float d = d2_exact(px[k], py[k], pz[k], lx, ly, lz);
                float nd = fminf(dist[k], d);
                dist[k] = nd;
                bool gt = nd > bv[c];       // strict >: lowest k on ties
                bv[c] = gt ? nd : bv[c];
                bk[c] = gt ? k : bk[c];
            }
            bool g1 = bv[1] > bv[0];
            float v01 = g1 ? bv[1] : bv[0];
            int   k01 = g1 ? bk[1] : bk[0];
            bool g3 = bv[3] > bv[2];
            float v23 = g3 ? bv[3] : bv[2];
            int   k23 = g3 ? bk[3] : bk[2];
            bool gf = v23 > v01;
            float bvf = gf ? v23 : v01;
            int   bkf = gf ? k23 : k01;

            int bp = tid + (bkf << 8);      // FPS_T == 256
            unsigned long long key =
                ((unsigned long long)__float_as_uint(bvf) << 32) |
                (unsigned)(~bp);

            // wave max via DPP; cross-wave via 4 LDS slots, parity dbuf.
            key = kmax64(key, dpp_k<0x111, 0xf>(key));
            key = kmax64(key, dpp_k<0x112, 0xf>(key));
            key = kmax64(key, dpp_k<0x114, 0xf>(key));
            key = kmax64(key, dpp_k<0x118, 0xf>(key));
            key = kmax64(key, dpp_k<0x142, 0xa>(key));
            key = kmax64(key, dpp_k<0x143, 0xc>(key));
            if (lane == 63) redk[par][wave] = key;
            barrier_lds_only();

            unsigned long long g =
                kmax64(kmax64(redk[par][0], redk[par][1]),
                       kmax64(redk[par][2], redk[par][3]));
            int p = (int)(~(unsigned)(g & 0xffffffffULL));
            p = __builtin_amdgcn_readfirstlane(p);   // uniform
            // winner coords from LDS broadcast (uniform addr, ~120cy) —
            // replaces the ~200cy L2 scalar load on the serial path.
            lx = sxyz[p * 3 + 0];
            ly = sxyz[p * 3 + 1];
            lz = sxyz[p * 3 + 2];
            cur = p;

            // publish chunk of 16 selected indices (fire-and-forget agent
            // atomics; never drained inside the loop).
            if (((it & 15) == 15) && tid < 16) {
                int t = (it & ~15) + tid;
                __hip_atomic_store(idxg + t, sel_hist[t], __ATOMIC_RELAXED,
                                   __HIP_MEMORY_SCOPE_AGENT);
            }
        }
        __syncthreads();

        // final gather of new_xyz / new_normal (host-visible outputs)
        const float* bn = normal + (size_t)b * NN * 3;
        for (int t = tid; t < NPOINT; t += FPS_T) {
            int i = sel_hist[t];
            size_t o = ((size_t)b * NPOINT + t) * 3;
            out_xyz[o + 0] = sxyz[i * 3 + 0];
            out_xyz[o + 1] = sxyz[i * 3 + 1];
            out_xyz[o + 2] = sxyz[i * 3 + 2];
            out_normal[o + 0] = bn[i * 3 + 0];
            out_normal[o + 1] = bn[i * 3 + 1];
            out_normal[o + 2] = bn[i * 3 + 2];
        }
    } else {
        // ================= consumer: ball query + MLP + maxpool ============
        int*   sel_all  = (int*)smem;                    // [4][32]
        float* bufA_all = (float*)(smem + 512);          // [4][2080]
        float* bufB_all = (float*)(smem + 33792);        // [4][2080]

        const int cb = blockIdx.x - NB;      // 0..247
        const int wave = threadIdx.x >> 6;   // 0..3
        const int lane = threadIdx.x & 63;
        int*   sel = sel_all + wave * 32;
        float* XA  = bufA_all + wave * 2080;
        float* XB  = bufB_all + wave * 2080;

        for (int pass = 0; pass < NPASS; ++pass) {
            int k = pass * SLOTS_PER_PASS + (cb * K2_WAVES + wave);
            if (k >= NB * NPOINT) k -= NB * NPOINT;  // dummies redo early
                                                     // centroids (identical
                                                     // rewrites: benign)
            const int b = k & 7;
            const int t = k >> 3;
            const int g = (b << 10) + t;
            const int p = t;
            const float* bxp = xyz + (size_t)b * NN * 3;
            const float* bfp = features + (size_t)b * NN * NC;

            // wait until the producer has published this centroid's index
            int v = __hip_atomic_load(idxbuf + g, __ATOMIC_RELAXED,
                                      __HIP_MEMORY_SCOPE_AGENT);
            while (v < 0) {
                __builtin_amdgcn_s_sleep(8);
                v = __hip_atomic_load(idxbuf + g, __ATOMIC_RELAXED,
                                      __HIP_MEMORY_SCOPE_AGENT);
            }
            const float cx = bxp[v * 3 + 0];
            const float cy = bxp[v * 3 + 1];
            const float cz = bxp[v * 3 + 2];

            // ---- ball query: first NSAMPLE hits in ascending index order --
            int have = 0;
            for (int ch = 0; ch < NN / 64 && have < NSAMPLE; ++ch) {
                int j = ch * 64 + lane;
                float x = bxp[j * 3 + 0], y = bxp[j * 3 + 1], z = bxp[j * 3 + 2];
                float d2 = d2_exact(x, y, z, cx, cy, cz);
                bool hit = d2 < 0.04f;   // strict f32 compare
                unsigned long long m = __ballot(hit);
                int pos = have + __popcll(m & ((1ull << lane) - 1ull));
                if (hit && pos < NSAMPLE) sel[pos] = j;
                have += __popcll(m);
            }
            __syncthreads();
            int nsel = have < NSAMPLE ? have : NSAMPLE;
            int first = sel[0];   // centroid itself always hits -> nsel >= 1
            if (lane < NSAMPLE && lane >= nsel) sel[lane] = first;
            __syncthreads();

            // ---- gather X = [rel_xyz(3) | features(32)] into LDS ----------
            {
                int s = lane >> 1, h = lane & 1;
                int row = sel[s];
                const float* fr = bfp + (size_t)row * NC + h * 16;
#pragma unroll
                for (int q = 0; q < 4; ++q) {
                    float4 vv = *(const float4*)(fr + q * 4);
                    int base = s * XS + 3 + h * 16 + q * 4;
                    XA[base + 0] = vv.x; XA[base + 1] = vv.y;
                    XA[base + 2] = vv.z; XA[base + 3] = vv.w;
                }
                if (h == 0) {
                    XA[s * XS + 0] = __fsub_rn(bxp[row * 3 + 0], cx);
                    XA[s * XS + 1] = __fsub_rn(bxp[row * 3 + 1], cy);
                    XA[s * XS + 2] = __fsub_rn(bxp[row * 3 + 2], cz);
                }
            }
            __syncthreads();

            const int sg = lane >> 3;   // 0..7 -> samples sg*4 .. sg*4+3
            const int og = lane & 7;    // output-channel group

            // ---- layer 1: 35 -> 64 ---------------------------------------
            {
                float acc[4][8];
#pragma unroll
                for (int j = 0; j < 4; ++j)
#pragma unroll
                    for (int o = 0; o < 8; ++o) acc[j][o] = 0.f;
                for (int c = 0; c < 35; ++c) {
                    float xv[4];
#pragma unroll
                    for (int j = 0; j < 4; ++j) xv[j] = XA[(sg * 4 + j) * XS + c];
                    const float* wr = w1 + c * 64 + og * 8;
                    float4 wa = *(const float4*)(wr);
                    float4 wb = *(const float4*)(wr + 4);
                    float w8[8] = {wa.x, wa.y, wa.z, wa.w, wb.x, wb.y, wb.z, wb.w};
#pragma unroll
                    for (int j = 0; j < 4; ++j)
#pragma unroll
                        for (int o = 0; o < 8; ++o) acc[j][o] += xv[j] * w8[o];
                }
                float4 ba = *(const float4*)(b1 + og * 8);
                float4 bb = *(const float4*)(b1 + og * 8 + 4);
                float bias[8] = {ba.x, ba.y, ba.z, ba.w, bb.x, bb.y, bb.z, bb.w};
#pragma unroll
                for (int j = 0; j < 4; ++j)
#pragma unroll
                    for (int o = 0; o < 8; ++o)
                        XB[(sg * 4 + j) * HS + og * 8 + o] =
                            fmaxf(acc[j][o] + bias[o], 0.f);
            }
            __syncthreads();

            // ---- layer 2: 64 -> 64 ---------------------------------------
            {
                float acc[4][8];
#pragma unroll
                for (int j = 0; j < 4; ++j)
#pragma unroll
                    for (int o = 0; o < 8; ++o) acc[j][o] = 0.f;
                for (int c = 0; c < 64; ++c) {
                    float xv[4];
#pragma unroll
                    for (int j = 0; j < 4; ++j) xv[j] = XB[(sg * 4 + j) * HS + c];
                    const float* wr = w2 + c * 64 + og * 8;
                    float4 wa = *(const float4*)(wr);
                    float4 wb = *(const float4*)(wr + 4);
                    float w8[8] = {wa.x, wa.y, wa.z, wa.w, wb.x, wb.y, wb.z, wb.w};
#pragma unroll
                    for (int j = 0; j < 4; ++j)
#pragma unroll
                        for (int o = 0; o < 8; ++o) acc[j][o] += xv[j] * w8[o];
                }
                float4 ba = *(const float4*)(b2 + og * 8);
                float4 bb = *(const float4*)(b2 + og * 8 + 4);
                float bias[8] = {ba.x, ba.y, ba.z, ba.w, bb.x, bb.y, bb.z, bb.w};
#pragma unroll
                for (int j = 0; j < 4; ++j)
#pragma unroll
                    for (int o = 0; o < 8; ++o)
                        XA[(sg * 4 + j) * HS + og * 8 + o] =
                            fmaxf(acc[j][o] + bias[o], 0.f);
            }
            __syncthreads();

            // ---- layer 3: 64 -> 128, maxpool over 32 samples -------------
            {
                float acc[4][16];
#pragma unroll
                for (int j = 0; j < 4; ++j)
#pragma unroll
                    for (int o = 0; o < 16; ++o) acc[j][o] = 0.f;
                for (int c = 0; c < 64; ++c) {
                    float xv[4];
#pragma unroll
                    for (int j = 0; j < 4; ++j) xv[j] = XA[(sg * 4 + j) * HS + c];
                    const float* wr = w3 + c * 128 + og * 16;
                    float4 wq[4];
#pragma unroll
                    for (int q = 0; q < 4; ++q) wq[q] = *(const float4*)(wr + q * 4);
                    float w16[16] = {wq[0].x, wq[0].y, wq[0].z, wq[0].w,
                                     wq[1].x, wq[1].y, wq[1].z, wq[1].w,
                                     wq[2].x, wq[2].y, wq[2].z, wq[2].w,
                                     wq[3].x, wq[3].y, wq[3].z, wq[3].w};
#pragma unroll
                    for (int j = 0; j < 4; ++j)
#pragma unroll
                        for (int o = 0; o < 16; ++o) acc[j][o] += xv[j] * w16[o];
                }
                float m[16];
#pragma unroll
                for (int o = 0; o < 16; ++o) {
                    float t0 = fmaxf(acc[0][o], acc[1][o]);
                    float t1 = fmaxf(acc[2][o], acc[3][o]);
                    m[o] = fmaxf(t0, t1);
                }
#pragma unroll
                for (int off = 8; off <= 32; off <<= 1)
#pragma unroll
                    for (int o = 0; o < 16; ++o)
                        m[o] = fmaxf(m[o], __shfl_xor(m[o], off));
                if (sg == 0) {
                    float4 bq[4];
#pragma unroll
                    for (int q = 0; q < 4; ++q)
                        bq[q] = *(const float4*)(b3 + og * 16 + q * 4);
                    float bias[16] = {bq[0].x, bq[0].y, bq[0].z, bq[0].w,
                                      bq[1].x, bq[1].y, bq[1].z, bq[1].w,
                                      bq[2].x, bq[2].y, bq[2].z, bq[2].w,
                                      bq[3].x, bq[3].y, bq[3].z, bq[3].w};
#pragma unroll
                    for (int o = 0; o < 16; ++o) {
                        float val = fmaxf(m[o] + bias[o], 0.f);
                        out_feat[((size_t)b * 128 + og * 16 + o) * NPOINT + p] = val;
                    }
                }
            }
            // bufA reread next pass only after the pass's early barriers.
        }
    }
}

// ---------------------------------------------------------------------------
__global__ void init_ws(int* __restrict__ idxbuf) {
    int i = blockIdx.x * blockDim.x + threadIdx.x;
    if (i < NB * NPOINT) idxbuf[i] = -1;
}

// ---------------------------------------------------------------------------
extern "C" void kernel_launch(void* const* d_in, const int* in_sizes, int n_in,
                              void* d_out, int out_size, void* d_ws, size_t ws_size,
                              hipStream_t stream) {
    const float* xyz      = (const float*)d_in[0];
    const float* normal   = (const float*)d_in[1];
    const float* features = (const float*)d_in[2];
    const float* w1 = (const float*)d_in[3];
    const float* b1 = (const float*)d_in[4];
    const float* w2 = (const float*)d_in[5];
    const float* b2 = (const float*)d_in[6];
    const float* w3 = (const float*)d_in[7];
    const float* b3 = (const float*)d_in[8];

    float* out        = (float*)d_out;
    float* out_xyz    = out;                       // (8,1024,3)
    float* out_normal = out + NB * NPOINT * 3;     // (8,1024,3)
    float* out_feat   = out + 2 * NB * NPOINT * 3; // (8,128,1024)
    int*   idxbuf     = (int*)d_ws;                // 8192 ints, re-inited

    hipLaunchKernelGGL(init_ws, dim3(32), dim3(256), 0, stream, idxbuf);

    void* args[] = {(void*)&xyz, (void*)&normal, (void*)&features,
                    (void*)&w1, (void*)&b1, (void*)&w2, (void*)&b2,
                    (void*)&w3, (void*)&b3,
                    (void*)&out_xyz, (void*)&out_normal, (void*)&out_feat,
                    (void*)&idxbuf};
    hipError_t e = hipLaunchCooperativeKernel(
        reinterpret_cast<void*>(fused_kernel), dim3(NBLK), dim3(256),
        args, 0, stream);
    if (e != hipSuccess) {
        // 256 blocks at 1 block/CU on a 256-CU chip are co-resident in
        // practice; fallback keeps us alive if cooperative launch is
        // rejected (e.g. under graph capture on some ROCm versions).
        hipLaunchKernelGGL(fused_kernel, dim3(NBLK), dim3(256), 0, stream,
                           xyz, normal, features, w1, b1, w2, b2, w3, b3,
                           out_xyz, out_normal, out_feat, idxbuf);
    }
}

// Round 4
// 1024.808 us; speedup vs baseline: 1.0547x; 1.0547x over previous
//
#include <hip/hip_runtime.h>

#define NB 8
#define NN 8192
#define NC 32
#define NPOINT 1024
#define NSAMPLE 32

// Exact round-to-nearest distance, no fma contraction: matches numpy
// ((dx*dx + dy*dy) + dz*dz) bitwise.
__device__ __forceinline__ float d2_exact(float ax, float ay, float az,
                                          float bx, float by, float bz) {
    float dx = __fsub_rn(ax, bx);
    float dy = __fsub_rn(ay, by);
    float dz = __fsub_rn(az, bz);
    return __fadd_rn(__fadd_rn(__fmul_rn(dx, dx), __fmul_rn(dy, dy)),
                     __fmul_rn(dz, dz));
}

// ---------------------------------------------------------------------------
// Round-7: fused producer/consumer (round-2 structure) with three fixes:
//   (1) round-3's in-loop VGPR pin REVERTED (it added copy traffic, +34us;
//       gfx950 VALU reads AGPRs directly, so AGPR residency was never the
//       cost — theory retired). Pre-loop pin only, as in the 969us version.
//   (2) 64-bit argmax key max via v_max_f64: key = (f32bits(dist)<<32)|~p
//       is a non-negative finite f64 pattern (dist in [0,1e10] keeps the
//       f64 exponent field < 0x7FF), and u64 order == f64 order for such
//       patterns (denormals included; f64 never flushes). Each DPP stage
//       drops from {2 dpp + cmp + 2 cndmask} to {2 dpp + v_max_f64},
//       shortening the serial reduce chain by ~80-100 cyc/iter.
//   (3) init kernel -> hipMemsetAsync, cooperative -> plain launch. Round 0
//       (two plain launches) had ~0 dispatch gap; rounds 2/3 (cooperative +
//       init kernel) had ~75us of gap. Plain launch is deadlock-free here:
//       producers are blocks 0..7 (dispatched first), consumers wait only
//       on producer-published data, never on other consumers.
// Kept from round 3 (plausibly neutral-positive, bisect next if needed):
// LDS-staged coords for the winner fetch, LDS-only in-loop barrier,
// 4-chain argmax scan.
// ---------------------------------------------------------------------------
#define FPS_T 256
#define FPS_K (NN / FPS_T)   // 32 points per thread
#define NCONS 248
#define NBLK (NB + NCONS)    // 256 blocks, 1 per CU
#define K2_WAVES 4
#define SLOTS_PER_PASS (NCONS * K2_WAVES)                              // 992
#define NPASS ((NB * NPOINT + SLOTS_PER_PASS - 1) / SLOTS_PER_PASS)    // 9

#define XS 37   // X row stride (35 cols + pad)
#define HS 65   // H row stride (64 cols + pad)

// shared-memory union layout (bytes):
//   producer: redk[2][4] ull @0 (64), sel_hist[1024] int @64 (4096),
//             sxyz[8192*3] f32 @4160 (98304)  -> 102464 used
//   consumer: sel_s[4][32] int @0 (512), bufA[4][2080] f32 @512 (33280),
//             bufB[4][2080] f32 @33792 (33280) -> 67072 used
// 102464 > 81920 guarantees 1 block/CU (2 blocks would exceed 160 KB).
#define SMEM_BYTES 102464

// u64 max implemented as v_max_f64 (valid for our key domain, see header).
__device__ __forceinline__ unsigned long long kmax64(unsigned long long a,
                                                     unsigned long long b) {
    double r = fmax(__longlong_as_double((long long)a),
                    __longlong_as_double((long long)b));
    return (unsigned long long)__double_as_longlong(r);
}

template <int CTRL, int RM>
__device__ __forceinline__ unsigned long long dpp_k(unsigned long long k) {
    unsigned hi = (unsigned)__builtin_amdgcn_update_dpp(
        0, (int)(k >> 32), CTRL, RM, 0xf, true);
    unsigned lo = (unsigned)__builtin_amdgcn_update_dpp(
        0, (int)(k & 0xffffffffULL), CTRL, RM, 0xf, true);
    return ((unsigned long long)hi << 32) | lo;
}

// Workgroup barrier that drains LDS ops only (no vmcnt(0)): keeps the
// fire-and-forget publish atomics off the barrier critical path.
__device__ __forceinline__ void barrier_lds_only() {
    asm volatile("s_waitcnt lgkmcnt(0)\n\ts_barrier" ::: "memory");
}

__global__ __launch_bounds__(256, 1) void fused_kernel(
    const float* __restrict__ xyz, const float* __restrict__ normal,
    const float* __restrict__ features,
    const float* __restrict__ w1, const float* __restrict__ b1,
    const float* __restrict__ w2, const float* __restrict__ b2,
    const float* __restrict__ w3, const float* __restrict__ b3,
    float* __restrict__ out_xyz, float* __restrict__ out_normal,
    float* __restrict__ out_feat, int* __restrict__ idxbuf) {

    __shared__ __align__(16) char smem[SMEM_BYTES];

    if (blockIdx.x < NB) {
        // ================= producer: FPS ===================================
        unsigned long long (*redk)[4] = (unsigned long long (*)[4])(smem);
        int*   sel_hist = (int*)(smem + 64);
        float* sxyz     = (float*)(smem + 64 + 4096);

        const int b = blockIdx.x;
        const float* bx = xyz + (size_t)b * NN * 3;
        const int tid = threadIdx.x;
        const int lane = tid & 63;
        const int wave = tid >> 6;   // 0..3
        int* idxg = idxbuf + (b << 10);

        float px[FPS_K], py[FPS_K], pz[FPS_K], dist[FPS_K];
#pragma unroll
        for (int k = 0; k < FPS_K; ++k) {
            int p = tid + k * FPS_T;
            float x = bx[p * 3 + 0];
            float y = bx[p * 3 + 1];
            float z = bx[p * 3 + 2];
            px[k] = x; py[k] = y; pz[k] = z;
            sxyz[p * 3 + 0] = x;
            sxyz[p * 3 + 1] = y;
            sxyz[p * 3 + 2] = z;
            dist[k] = 1e10f;
        }
        // Pin the coordinate arrays (pre-loop only, round-0 style): opaque
        // asm stops the compiler from sinking the global loads into the loop.
#pragma unroll
        for (int k = 0; k < FPS_K; ++k) {
            asm volatile("" : "+v"(px[k]), "+v"(py[k]), "+v"(pz[k]));
        }

        int cur = 0;
        float lx = bx[0], ly = bx[1], lz = bx[2];

        for (int it = 0; it < NPOINT; ++it) {
            const int par = it & 1;
            if (tid == 0) sel_hist[it] = cur;

            // 4 independent argmax chains over contiguous k-ranges
            // (dep depth 8 instead of 32). Lower chain owns lower k ->
            // strict > at every combine keeps first occurrence.
            float bv[4] = {-1.0f, -1.0f, -1.0f, -1.0f};
            int bk[4] = {0, 0, 0, 0};
#pragma unroll
            for (int k = 0; k < FPS_K; ++k) {
                const int c = k >> 3;
                float d = d2_exact(px[k], py[k], pz[k], lx, ly, lz);
                float nd = fminf(dist[k], d);
                dist[k] = nd;
                bool gt = nd > bv[c];       // strict >: lowest k on ties
                bv[c] = gt ? nd : bv[c];
                bk[c] = gt ? k : bk[c];
            }
            bool g1 = bv[1] > bv[0];
            float v01 = g1 ? bv[1] : bv[0];
            int   k01 = g1 ? bk[1] : bk[0];
            bool g3 = bv[3] > bv[2];
            float v23 = g3 ? bv[3] : bv[2];
            int   k23 = g3 ? bk[3] : bk[2];
            bool gf = v23 > v01;
            float bvf = gf ? v23 : v01;
            int   bkf = gf ? k23 : k01;

            int bp = tid + (bkf << 8);      // FPS_T == 256
            unsigned long long key =
                ((unsigned long long)__float_as_uint(bvf) << 32) |
                (unsigned)(~bp);

            // wave max via DPP (each stage: 2 dpp + 1 v_max_f64);
            // cross-wave via 4 LDS slots, parity dbuf.
            key = kmax64(key, dpp_k<0x111, 0xf>(key));
            key = kmax64(key, dpp_k<0x112, 0xf>(key));
            key = kmax64(key, dpp_k<0x114, 0xf>(key));
            key = kmax64(key, dpp_k<0x118, 0xf>(key));
            key = kmax64(key, dpp_k<0x142, 0xa>(key));
            key = kmax64(key, dpp_k<0x143, 0xc>(key));
            if (lane == 63) redk[par][wave] = key;
            barrier_lds_only();

            unsigned long long g =
                kmax64(kmax64(redk[par][0], redk[par][1]),
                       kmax64(redk[par][2], redk[par][3]));
            int p = (int)(~(unsigned)(g & 0xffffffffULL));
            p = __builtin_amdgcn_readfirstlane(p);   // uniform
            // winner coords from LDS broadcast (uniform addr, ~120cy) —
            // replaces the ~200cy L2 scalar load on the serial path.
            lx = sxyz[p * 3 + 0];
            ly = sxyz[p * 3 + 1];
            lz = sxyz[p * 3 + 2];
            cur = p;

            // publish chunk of 16 selected indices (fire-and-forget agent
            // atomics; never drained inside the loop).
            if (((it & 15) == 15) && tid < 16) {
                int t = (it & ~15) + tid;
                __hip_atomic_store(idxg + t, sel_hist[t], __ATOMIC_RELAXED,
                                   __HIP_MEMORY_SCOPE_AGENT);
            }
        }
        __syncthreads();

        // final gather of new_xyz / new_normal (host-visible outputs)
        const float* bn = normal + (size_t)b * NN * 3;
        for (int t = tid; t < NPOINT; t += FPS_T) {
            int i = sel_hist[t];
            size_t o = ((size_t)b * NPOINT + t) * 3;
            out_xyz[o + 0] = sxyz[i * 3 + 0];
            out_xyz[o + 1] = sxyz[i * 3 + 1];
            out_xyz[o + 2] = sxyz[i * 3 + 2];
            out_normal[o + 0] = bn[i * 3 + 0];
            out_normal[o + 1] = bn[i * 3 + 1];
            out_normal[o + 2] = bn[i * 3 + 2];
        }
    } else {
        // ================= consumer: ball query + MLP + maxpool ============
        int*   sel_all  = (int*)smem;                    // [4][32]
        float* bufA_all = (float*)(smem + 512);          // [4][2080]
        float* bufB_all = (float*)(smem + 33792);        // [4][2080]

        const int cb = blockIdx.x - NB;      // 0..247
        const int wave = threadIdx.x >> 6;   // 0..3
        const int lane = threadIdx.x & 63;
        int*   sel = sel_all + wave * 32;
        float* XA  = bufA_all + wave * 2080;
        float* XB  = bufB_all + wave * 2080;

        for (int pass = 0; pass < NPASS; ++pass) {
            int k = pass * SLOTS_PER_PASS + (cb * K2_WAVES + wave);
            if (k >= NB * NPOINT) k -= NB * NPOINT;  // dummies redo early
                                                     // centroids (identical
                                                     // rewrites: benign)
            const int b = k & 7;
            const int t = k >> 3;
            const int g = (b << 10) + t;
            const int p = t;
            const float* bxp = xyz + (size_t)b * NN * 3;
            const float* bfp = features + (size_t)b * NN * NC;

            // wait until the producer has published this centroid's index
            int v = __hip_atomic_load(idxbuf + g, __ATOMIC_RELAXED,
                                      __HIP_MEMORY_SCOPE_AGENT);
            while (v < 0) {
                __builtin_amdgcn_s_sleep(8);
                v = __hip_atomic_load(idxbuf + g, __ATOMIC_RELAXED,
                                      __HIP_MEMORY_SCOPE_AGENT);
            }
            const float cx = bxp[v * 3 + 0];
            const float cy = bxp[v * 3 + 1];
            const float cz = bxp[v * 3 + 2];

            // ---- ball query: first NSAMPLE hits in ascending index order --
            int have = 0;
            for (int ch = 0; ch < NN / 64 && have < NSAMPLE; ++ch) {
                int j = ch * 64 + lane;
                float x = bxp[j * 3 + 0], y = bxp[j * 3 + 1], z = bxp[j * 3 + 2];
                float d2 = d2_exact(x, y, z, cx, cy, cz);
                bool hit = d2 < 0.04f;   // strict f32 compare
                unsigned long long m = __ballot(hit);
                int pos = have + __popcll(m & ((1ull << lane) - 1ull));
                if (hit && pos < NSAMPLE) sel[pos] = j;
                have += __popcll(m);
            }
            __syncthreads();
            int nsel = have < NSAMPLE ? have : NSAMPLE;
            int first = sel[0];   // centroid itself always hits -> nsel >= 1
            if (lane < NSAMPLE && lane >= nsel) sel[lane] = first;
            __syncthreads();

            // ---- gather X = [rel_xyz(3) | features(32)] into LDS ----------
            {
                int s = lane >> 1, h = lane & 1;
                int row = sel[s];
                const float* fr = bfp + (size_t)row * NC + h * 16;
#pragma unroll
                for (int q = 0; q < 4; ++q) {
                    float4 vv = *(const float4*)(fr + q * 4);
                    int base = s * XS + 3 + h * 16 + q * 4;
                    XA[base + 0] = vv.x; XA[base + 1] = vv.y;
                    XA[base + 2] = vv.z; XA[base + 3] = vv.w;
                }
                if (h == 0) {
                    XA[s * XS + 0] = __fsub_rn(bxp[row * 3 + 0], cx);
                    XA[s * XS + 1] = __fsub_rn(bxp[row * 3 + 1], cy);
                    XA[s * XS + 2] = __fsub_rn(bxp[row * 3 + 2], cz);
                }
            }
            __syncthreads();

            const int sg = lane >> 3;   // 0..7 -> samples sg*4 .. sg*4+3
            const int og = lane & 7;    // output-channel group

            // ---- layer 1: 35 -> 64 ---------------------------------------
            {
                float acc[4][8];
#pragma unroll
                for (int j = 0; j < 4; ++j)
#pragma unroll
                    for (int o = 0; o < 8; ++o) acc[j][o] = 0.f;
                for (int c = 0; c < 35; ++c) {
                    float xv[4];
#pragma unroll
                    for (int j = 0; j < 4; ++j) xv[j] = XA[(sg * 4 + j) * XS + c];
                    const float* wr = w1 + c * 64 + og * 8;
                    float4 wa = *(const float4*)(wr);
                    float4 wb = *(const float4*)(wr + 4);
                    float w8[8] = {wa.x, wa.y, wa.z, wa.w, wb.x, wb.y, wb.z, wb.w};
#pragma unroll
                    for (int j = 0; j < 4; ++j)
#pragma unroll
                        for (int o = 0; o < 8; ++o) acc[j][o] += xv[j] * w8[o];
                }
                float4 ba = *(const float4*)(b1 + og * 8);
                float4 bb = *(const float4*)(b1 + og * 8 + 4);
                float bias[8] = {ba.x, ba.y, ba.z, ba.w, bb.x, bb.y, bb.z, bb.w};
#pragma unroll
                for (int j = 0; j < 4; ++j)
#pragma unroll
                    for (int o = 0; o < 8; ++o)
                        XB[(sg * 4 + j) * HS + og * 8 + o] =
                            fmaxf(acc[j][o] + bias[o], 0.f);
            }
            __syncthreads();

            // ---- layer 2: 64 -> 64 ---------------------------------------
            {
                float acc[4][8];
#pragma unroll
                for (int j = 0; j < 4; ++j)
#pragma unroll
                    for (int o = 0; o < 8; ++o) acc[j][o] = 0.f;
                for (int c = 0; c < 64; ++c) {
                    float xv[4];
#pragma unroll
                    for (int j = 0; j < 4; ++j) xv[j] = XB[(sg * 4 + j) * HS + c];
                    const float* wr = w2 + c * 64 + og * 8;
                    float4 wa = *(const float4*)(wr);
                    float4 wb = *(const float4*)(wr + 4);
                    float w8[8] = {wa.x, wa.y, wa.z, wa.w, wb.x, wb.y, wb.z, wb.w};
#pragma unroll
                    for (int j = 0; j < 4; ++j)
#pragma unroll
                        for (int o = 0; o < 8; ++o) acc[j][o] += xv[j] * w8[o];
                }
                float4 ba = *(const float4*)(b2 + og * 8);
                float4 bb = *(const float4*)(b2 + og * 8 + 4);
                float bias[8] = {ba.x, ba.y, ba.z, ba.w, bb.x, bb.y, bb.z, bb.w};
#pragma unroll
                for (int j = 0; j < 4; ++j)
#pragma unroll
                    for (int o = 0; o < 8; ++o)
                        XA[(sg * 4 + j) * HS + og * 8 + o] =
                            fmaxf(acc[j][o] + bias[o], 0.f);
            }
            __syncthreads();

            // ---- layer 3: 64 -> 128, maxpool over 32 samples -------------
            {
                float acc[4][16];
#pragma unroll
                for (int j = 0; j < 4; ++j)
#pragma unroll
                    for (int o = 0; o < 16; ++o) acc[j][o] = 0.f;
                for (int c = 0; c < 64; ++c) {
                    float xv[4];
#pragma unroll
                    for (int j = 0; j < 4; ++j) xv[j] = XA[(sg * 4 + j) * HS + c];
                    const float* wr = w3 + c * 128 + og * 16;
                    float4 wq[4];
#pragma unroll
                    for (int q = 0; q < 4; ++q) wq[q] = *(const float4*)(wr + q * 4);
                    float w16[16] = {wq[0].x, wq[0].y, wq[0].z, wq[0].w,
                                     wq[1].x, wq[1].y, wq[1].z, wq[1].w,
                                     wq[2].x, wq[2].y, wq[2].z, wq[2].w,
                                     wq[3].x, wq[3].y, wq[3].z, wq[3].w};
#pragma unroll
                    for (int j = 0; j < 4; ++j)
#pragma unroll
                        for (int o = 0; o < 16; ++o) acc[j][o] += xv[j] * w16[o];
                }
                float m[16];
#pragma unroll
                for (int o = 0; o < 16; ++o) {
                    float t0 = fmaxf(acc[0][o], acc[1][o]);
                    float t1 = fmaxf(acc[2][o], acc[3][o]);
                    m[o] = fmaxf(t0, t1);
                }
#pragma unroll
                for (int off = 8; off <= 32; off <<= 1)
#pragma unroll
                    for (int o = 0; o < 16; ++o)
                        m[o] = fmaxf(m[o], __shfl_xor(m[o], off));
                if (sg == 0) {
                    float4 bq[4];
#pragma unroll
                    for (int q = 0; q < 4; ++q)
                        bq[q] = *(const float4*)(b3 + og * 16 + q * 4);
                    float bias[16] = {bq[0].x, bq[0].y, bq[0].z, bq[0].w,
                                      bq[1].x, bq[1].y, bq[1].z, bq[1].w,
                                      bq[2].x, bq[2].y, bq[2].z, bq[2].w,
                                      bq[3].x, bq[3].y, bq[3].z, bq[3].w};
#pragma unroll
                    for (int o = 0; o < 16; ++o) {
                        float val = fmaxf(m[o] + bias[o], 0.f);
                        out_feat[((size_t)b * 128 + og * 16 + o) * NPOINT + p] = val;
                    }
                }
            }
            // bufA reread next pass only after the pass's early barriers.
        }
    }
}

// ---------------------------------------------------------------------------
extern "C" void kernel_launch(void* const* d_in, const int* in_sizes, int n_in,
                              void* d_out, int out_size, void* d_ws, size_t ws_size,
                              hipStream_t stream) {
    const float* xyz      = (const float*)d_in[0];
    const float* normal   = (const float*)d_in[1];
    const float* features = (const float*)d_in[2];
    const float* w1 = (const float*)d_in[3];
    const float* b1 = (const float*)d_in[4];
    const float* w2 = (const float*)d_in[5];
    const float* b2 = (const float*)d_in[6];
    const float* w3 = (const float*)d_in[7];
    const float* b3 = (const float*)d_in[8];

    float* out        = (float*)d_out;
    float* out_xyz    = out;                       // (8,1024,3)
    float* out_normal = out + NB * NPOINT * 3;     // (8,1024,3)
    float* out_feat   = out + 2 * NB * NPOINT * 3; // (8,128,1024)
    int*   idxbuf     = (int*)d_ws;                // 8192 ints

    // 0xFF bytes -> every int == -1 (the "unpublished" sentinel).
    hipMemsetAsync(idxbuf, 0xFF, NB * NPOINT * sizeof(int), stream);

    hipLaunchKernelGGL(fused_kernel, dim3(NBLK), dim3(256), 0, stream,
                       xyz, normal, features, w1, b1, w2, b2, w3, b3,
                       out_xyz, out_normal, out_feat, idxbuf);
}